// Round 8
// baseline (12989.966 us; speedup 1.0000x reference)
//
#include <hip/hip_runtime.h>
#include <stdint.h>

// LSTM: B=256, T=512, D=128, H=512, C=10
// R8 phase pipelining: 64 blocks x 4 waves = 4 groups x 16 blocks.
// Each group owns 4 PHASES of 16 batches (64 batches/group) and round-robins
// them each timestep: publish phase p, serve p+1,p+2,p+3, return to p after
// ~3 visits — its h/flags have propagated, so the MALL sync latency is hidden
// behind the other phases' compute. Per wave: 8 hidden units, full K=640.
// A-tile packs 2 gates x 8 units; i,f,g,o recombined via shfl_xor(32).
// Sync per phase = R4-proven: 8B atomic h stores -> vmcnt(0) -> relaxed
// per-wave flag; consumers tight-poll 64 flags (one 4B load per lane).

#define T_STEPS 512
#define BATCH   256
#define DIM     128
#define HID     512
#define NPH     4     // phases per group
#define NGRP    4
#define BT      16    // batches per phase

typedef _Float16 half8 __attribute__((ext_vector_type(8)));
typedef _Float16 half4 __attribute__((ext_vector_type(4)));
typedef float    f32x4 __attribute__((ext_vector_type(4)));

#define SLOT_HALFS (BATCH * HID)
#define FLG_OFF    (2 * SLOT_HALFS * 2)            // 512 KiB h double-buffer
#define WS_NEEDED  (FLG_OFF + NGRP * NPH * 64 * 4) // + 4 KiB flags

__device__ __forceinline__ half8 cvt8(f32x4 a, f32x4 b) {
  half8 r;
  r[0]=(_Float16)a[0]; r[1]=(_Float16)a[1]; r[2]=(_Float16)a[2]; r[3]=(_Float16)a[3];
  r[4]=(_Float16)b[0]; r[5]=(_Float16)b[1]; r[6]=(_Float16)b[2]; r[7]=(_Float16)b[3];
  return r;
}
__device__ __forceinline__ half8 load8_cvt(const float* p) {
  const f32x4* q = (const f32x4*)p;
  return cvt8(q[0], q[1]);
}
__device__ __forceinline__ float fsig(float x) {
  return __builtin_amdgcn_rcpf(1.f + __expf(-x));
}
__device__ __forceinline__ float ftanh(float x) {
  return 1.f - 2.f * __builtin_amdgcn_rcpf(1.f + __expf(2.f * x));
}

union h4u { unsigned long long u; half4 h; };
union h8u { unsigned long long u2[2]; half8 h; };

__global__ __launch_bounds__(256, 1) void lstm_persistent(
    const float* __restrict__ X,   const float* __restrict__ Wih,
    const float* __restrict__ Whh, const float* __restrict__ bih,
    const float* __restrict__ bhh, const float* __restrict__ Wlin,
    float* __restrict__ out, _Float16* __restrict__ hbuf,
    unsigned* __restrict__ flg)
{
  const int tid  = threadIdx.x;
  const int w    = tid >> 6;
  const int lane = tid & 63;
  const int col  = lane & 15;         // batch-within-phase; also A-row index
  const int q    = lane >> 4;         // 0..3
  const int bid  = blockIdx.x;
  const int g    = bid & 3;           // group 0..3
  const int role = bid >> 2;          // 0..15
  const int wid  = role * 4 + w;      // wave id in group, 0..63
  const int U    = wid * 8;           // this wave's 8 hidden units [U, U+8)

  // A-tile row mapping: tile mt (0,1) covers gates {2mt, 2mt+1}; A-row index
  // a in [0,16): gate = 2*mt + (a>>3), unit = U + (a&7).
  half8 whh[16][2];                   // [k-chunk of 32][tile] = 128 VGPR
  half8 wih[4][2];                    // 32 VGPR
  {
    const int a = col;
    #pragma unroll
    for (int mt = 0; mt < 2; ++mt) {
      const int row = (2 * mt + (a >> 3)) * HID + U + (a & 7);
      #pragma unroll
      for (int kc = 0; kc < 16; ++kc)
        whh[kc][mt] = load8_cvt(Whh + (size_t)row * HID + kc * 32 + q * 8);
      #pragma unroll
      for (int xc = 0; xc < 4; ++xc)
        wih[xc][mt] = load8_cvt(Wih + (size_t)row * DIM + xc * 32 + q * 8);
    }
  }

  float bias[2][4];
  #pragma unroll
  for (int mt = 0; mt < 2; ++mt)
    #pragma unroll
    for (int r = 0; r < 4; ++r) {
      const int a = q * 4 + r;        // C/D row index in the tile
      const int row = (2 * mt + (a >> 3)) * HID + U + (a & 7);
      bias[mt][r] = bih[row] + bhh[row];
    }

  float c_st[NPH][4], hsum[NPH][4];
  #pragma unroll
  for (int p = 0; p < NPH; ++p)
    #pragma unroll
    for (int r = 0; r < 4; ++r) { c_st[p][r] = 0.f; hsum[p][r] = 0.f; }

  // per-phase batch / X base; prologue-load X(p, 0) into fp16 regs
  const float* Xb[NPH];
  half8 xh[NPH][4];                   // 64 VGPR
  #pragma unroll
  for (int p = 0; p < NPH; ++p) {
    const int b = (g * NPH + p) * BT + col;
    Xb[p] = X + (size_t)b * T_STEPS * DIM;
    #pragma unroll
    for (int xc = 0; xc < 4; ++xc)
      xh[p][xc] = load8_cvt(Xb[p] + xc * 32 + q * 8);
  }
  f32x4 xraw[8];                      // shared raw buffer for in-flight X load
  unsigned* flgbase = flg + g * NPH * 64;

  for (int t = 0; t < T_STEPS; ++t) {
    #pragma unroll
    for (int p = 0; p < NPH; ++p) {
      // 1. convert previous visit's X load (into xh[(p+3)&3])
      if (!(t == 0 && p == 0)) {
        asm volatile("s_waitcnt vmcnt(0)" ::: "memory");
        const int pp = (p + 3) & 3;
        #pragma unroll
        for (int xc = 0; xc < 4; ++xc)
          xh[pp][xc] = cvt8(xraw[2 * xc], xraw[2 * xc + 1]);
      }

      // 2. x-projection for this phase (registers only)
      f32x4 acc[2];
      acc[0] = (f32x4){0.f,0.f,0.f,0.f};
      acc[1] = (f32x4){0.f,0.f,0.f,0.f};
      #pragma unroll
      for (int xc = 0; xc < 4; ++xc)
        #pragma unroll
        for (int mt = 0; mt < 2; ++mt)
          acc[mt] = __builtin_amdgcn_mfma_f32_16x16x32_f16(wih[xc][mt], xh[p][xc], acc[mt], 0, 0, 0);

      const int b_my = (g * NPH + p) * BT + col;

      if (t > 0) {
        // 3. poll this phase's 64 per-wave flags (4B per lane, tight spin)
        unsigned* fl = flgbase + p * 64;
        const unsigned target = (unsigned)t;
        for (;;) {
          unsigned v = __hip_atomic_load(fl + lane, __ATOMIC_RELAXED,
                                         __HIP_MEMORY_SCOPE_AGENT);
          if (__all((int)(v >= target))) break;
        }
        __builtin_amdgcn_sched_barrier(0);

        // 4. h(t) B-frags (8B atomic loads, R4-proven) + recurrent MFMA
        const unsigned long long* hp =
            (const unsigned long long*)(hbuf + (size_t)(t & 1) * SLOT_HALFS
                                        + (size_t)b_my * HID) + q * 2;
        unsigned long long lo[16], hi[16];
        #pragma unroll
        for (int kc = 0; kc < 16; ++kc) {
          lo[kc] = __hip_atomic_load(hp + kc * 8,     __ATOMIC_RELAXED, __HIP_MEMORY_SCOPE_AGENT);
          hi[kc] = __hip_atomic_load(hp + kc * 8 + 1, __ATOMIC_RELAXED, __HIP_MEMORY_SCOPE_AGENT);
        }
        #pragma unroll
        for (int kc = 0; kc < 16; ++kc) {
          h8u u; u.u2[0] = lo[kc]; u.u2[1] = hi[kc];
          #pragma unroll
          for (int mt = 0; mt < 2; ++mt)
            acc[mt] = __builtin_amdgcn_mfma_f32_16x16x32_f16(whh[kc][mt], u.h, acc[mt], 0, 0, 0);
        }
      }

      // 5. gates: lane holds 2 gates x 4 units; partner (lane^32) the other 2
      h4u hv;
      {
        float v0[4], v1[4], p0[4], p1[4];
        #pragma unroll
        for (int r = 0; r < 4; ++r) {
          v0[r] = acc[0][r] + bias[0][r];
          v1[r] = acc[1][r] + bias[1][r];
          p0[r] = __shfl_xor(v0[r], 32, 64);
          p1[r] = __shfl_xor(v1[r], 32, 64);
        }
        const bool lowq = (q < 2);
        #pragma unroll
        for (int r = 0; r < 4; ++r) {
          const float iv = lowq ? v0[r] : p0[r];
          const float fv = lowq ? p0[r] : v0[r];
          const float gv = lowq ? v1[r] : p1[r];
          const float ov = lowq ? p1[r] : v1[r];
          const float cc = fsig(fv) * c_st[p][r] + fsig(iv) * ftanh(gv);
          c_st[p][r] = cc;
          const float h = fsig(ov) * ftanh(cc);
          hsum[p][r] += h;
          hv.h[r] = (_Float16)h;
        }
      }

      // 6. publish h(t+1) (q<2 lanes: units U+(q&1)*4 .. +3), drain, flag
      if (q < 2) {
        unsigned long long* hw =
            (unsigned long long*)(hbuf + (size_t)((t + 1) & 1) * SLOT_HALFS
                                  + (size_t)b_my * HID + U + (q & 1) * 4);
        __hip_atomic_store(hw, hv.u, __ATOMIC_RELAXED, __HIP_MEMORY_SCOPE_AGENT);
      }
      if (t + 1 < T_STEPS) {
        asm volatile("s_waitcnt vmcnt(0)" ::: "memory");
        if (lane == 0)
          __hip_atomic_store(flgbase + p * 64 + wid, (unsigned)(t + 1),
                             __ATOMIC_RELAXED, __HIP_MEMORY_SCOPE_AGENT);
      }

      // 7. issue X(p, t+1) raw loads (converted at next visit; ~3 visits of
      // slack before consumption at visit(p, t+1))
      {
        const int tn = (t + 1 < T_STEPS) ? (t + 1) : (T_STEPS - 1);
        const float* xp = Xb[p] + (size_t)tn * DIM + q * 8;
        #pragma unroll
        for (int xc = 0; xc < 4; ++xc) {
          const f32x4* src = (const f32x4*)(xp + xc * 32);
          xraw[2 * xc]     = src[0];
          xraw[2 * xc + 1] = src[1];
        }
      }
    }
  }

  // epilogue: logits += mean_h * W_lin^T per phase (bias pre-set by init)
  const float inv = 1.0f / (float)T_STEPS;
  #pragma unroll
  for (int p = 0; p < NPH; ++p) {
    const int b_my = (g * NPH + p) * BT + col;
    float m[4];
    #pragma unroll
    for (int r = 0; r < 4; ++r) m[r] = hsum[p][r] * inv;
    #pragma unroll
    for (int cls = 0; cls < 10; ++cls) {
      f32x4 wl = *(const f32x4*)(Wlin + (size_t)cls * HID + U + (q & 1) * 4);
      float pv = m[0]*wl[0] + m[1]*wl[1] + m[2]*wl[2] + m[3]*wl[3];
      pv += __shfl_xor(pv, 16, 64);   // q0+q1 (q2+q3 mirror, not stored)
      if (q == 0) atomicAdd(out + b_my * 10 + cls, pv);
    }
  }
}

__global__ void init_out(const float* __restrict__ blin, float* __restrict__ out) {
  const int i = blockIdx.x * blockDim.x + threadIdx.x;
  if (i < BATCH * 10) out[i] = blin[i % 10];
}

extern "C" void kernel_launch(void* const* d_in, const int* in_sizes, int n_in,
                              void* d_out, int out_size, void* d_ws, size_t ws_size,
                              hipStream_t stream) {
  const float* X    = (const float*)d_in[0];
  const float* Wih  = (const float*)d_in[1];
  const float* Whh  = (const float*)d_in[2];
  const float* bih  = (const float*)d_in[3];
  const float* bhh  = (const float*)d_in[4];
  const float* Wlin = (const float*)d_in[5];
  const float* blin = (const float*)d_in[6];
  float* out = (float*)d_out;

  if (ws_size < (size_t)WS_NEEDED) return;

  _Float16* hbuf = (_Float16*)d_ws;
  unsigned* flg  = (unsigned*)((char*)d_ws + FLG_OFF);

  hipMemsetAsync(d_ws, 0, WS_NEEDED, stream);
  init_out<<<10, 256, 0, stream>>>(blin, out);
  lstm_persistent<<<64, 256, 0, stream>>>(X, Wih, Whh, bih, bhh, Wlin, out,
                                          hbuf, flg);
}

// Round 9
// 3392.003 us; speedup vs baseline: 3.8296x; 3.8296x over previous
//
#include <hip/hip_runtime.h>
#include <stdint.h>

// LSTM: B=256, T=512, D=128, H=512, C=10
// R9 = R4 (proven 3.69ms) + X prefetch + xp-in-propagation-window.
// Persistent: 128 blocks x 4 waves. 16 groups x 8 blocks (g=bid&15); group
// owns 16 batches; each wave owns 16 hidden units (64 gate rows), K=640.
// W_ih/W_hh fragments live in the unified VGPR/AGPR file. h exchanged via
// relaxed agent-scope atomics (sc1, MALL-coherent). Per-wave flags; producer:
// h stores -> s_waitcnt vmcnt(0) -> relaxed flag store. Consumer: tight poll.
// NEW: X(t+1) raw-prefetched at loop top; xp(t+1) MFMA'd AFTER publishing
// h(t+1) — overlapping flag propagation — so the serial chain at step t+1 is
// only poll -> h-load -> h-MFMA -> gates.

#define T_STEPS 512
#define BATCH   256
#define DIM     128
#define HID     512
#define NGRP    16
#define BT      16

typedef _Float16 half8 __attribute__((ext_vector_type(8)));
typedef _Float16 half4 __attribute__((ext_vector_type(4)));
typedef float    f32x4 __attribute__((ext_vector_type(4)));

#define HBUF_HALFS (2 * BATCH * HID)
#define FLG_OFF    (HBUF_HALFS * 2)          // 524288 B
#define WS_NEEDED  (FLG_OFF + NGRP * 128)

__device__ __forceinline__ half8 cvt8(f32x4 a, f32x4 b) {
  half8 r;
  r[0]=(_Float16)a[0]; r[1]=(_Float16)a[1]; r[2]=(_Float16)a[2]; r[3]=(_Float16)a[3];
  r[4]=(_Float16)b[0]; r[5]=(_Float16)b[1]; r[6]=(_Float16)b[2]; r[7]=(_Float16)b[3];
  return r;
}
__device__ __forceinline__ half8 load8_cvt(const float* p) {
  const f32x4* q = (const f32x4*)p;
  return cvt8(q[0], q[1]);
}
__device__ __forceinline__ float fsig(float x) {
  return __builtin_amdgcn_rcpf(1.f + __expf(-x));
}
__device__ __forceinline__ float ftanh(float x) {
  return 1.f - 2.f * __builtin_amdgcn_rcpf(1.f + __expf(2.f * x));
}

union h4u { unsigned long long u; half4 h; };
union h8u { unsigned long long u2[2]; half8 h; };

__global__ __launch_bounds__(256, 1) void lstm_persistent(
    const float* __restrict__ X,   const float* __restrict__ Wih,
    const float* __restrict__ Whh, const float* __restrict__ bih,
    const float* __restrict__ bhh, const float* __restrict__ Wlin,
    float* __restrict__ out, _Float16* __restrict__ hbuf,
    unsigned* __restrict__ flg)
{
  const int tid  = threadIdx.x;
  const int w    = tid >> 6;
  const int lane = tid & 63;
  const int col  = lane & 15;        // batch-within-group (B/C col), W A-frag row
  const int q    = lane >> 4;        // 0..3
  const int bid  = blockIdx.x;
  const int g    = bid & 15;         // group
  const int blk  = bid >> 4;         // 0..7 within group
  const int J    = blk * 64 + w * 16;   // hidden-unit base owned by this wave
  const int wid  = blk * 4 + w;      // wave id in group, 0..31
  const int b_my = g * BT + col;     // this lane's batch

  // ---- W fragments into registers (once) ----
  half8 whh[16][4];                  // [k-chunk of 32][gate]
  half8 wih[4][4];
  #pragma unroll
  for (int kc = 0; kc < 16; ++kc)
    #pragma unroll
    for (int mt = 0; mt < 4; ++mt) {
      const int row = mt * HID + J + col;
      whh[kc][mt] = load8_cvt(Whh + (size_t)row * HID + kc * 32 + q * 8);
    }
  #pragma unroll
  for (int xc = 0; xc < 4; ++xc)
    #pragma unroll
    for (int mt = 0; mt < 4; ++mt) {
      const int row = mt * HID + J + col;
      wih[xc][mt] = load8_cvt(Wih + (size_t)row * DIM + xc * 32 + q * 8);
    }

  float bias[4][4], c_st[4], hsum[4];
  #pragma unroll
  for (int mt = 0; mt < 4; ++mt)
    #pragma unroll
    for (int r = 0; r < 4; ++r) {
      const int row = mt * HID + J + q * 4 + r;
      bias[mt][r] = bih[row] + bhh[row];
    }
  #pragma unroll
  for (int r = 0; r < 4; ++r) { c_st[r] = 0.f; hsum[r] = 0.f; }

  unsigned* myflg = flg + g * 32;    // 32 per-wave flags = one 128B line
  const float* Xb = X + (size_t)b_my * T_STEPS * DIM;

  // ---- prologue: X(0) prefetch + acc = xp(0) ----
  f32x4 xraw[8];
  #pragma unroll
  for (int xc = 0; xc < 4; ++xc) {
    const f32x4* p = (const f32x4*)(Xb + xc * 32 + q * 8);
    xraw[2 * xc] = p[0]; xraw[2 * xc + 1] = p[1];
  }
  f32x4 acc[4];
  #pragma unroll
  for (int mt = 0; mt < 4; ++mt) acc[mt] = (f32x4){0.f, 0.f, 0.f, 0.f};
  #pragma unroll
  for (int xc = 0; xc < 4; ++xc) {
    half8 xb = cvt8(xraw[2 * xc], xraw[2 * xc + 1]);
    #pragma unroll
    for (int mt = 0; mt < 4; ++mt)
      acc[mt] = __builtin_amdgcn_mfma_f32_16x16x32_f16(wih[xc][mt], xb, acc[mt], 0, 0, 0);
  }

  for (int t = 0; t < T_STEPS; ++t) {
    // issue X(t+1) raw prefetch (clamped; drained by publish vmcnt(0))
    {
      const int tn = (t + 1 < T_STEPS) ? (t + 1) : (T_STEPS - 1);
      const float* xp = Xb + (size_t)tn * DIM + q * 8;
      #pragma unroll
      for (int xc = 0; xc < 4; ++xc) {
        const f32x4* src = (const f32x4*)(xp + xc * 32);
        xraw[2 * xc]     = src[0];
        xraw[2 * xc + 1] = src[1];
      }
    }

    // wait for h(t): all 32 producer waves of this group at flag >= t
    if (t > 0) {
      const unsigned target = (unsigned)t;
      for (;;) {
        unsigned v = __hip_atomic_load(myflg + (lane & 31), __ATOMIC_RELAXED,
                                       __HIP_MEMORY_SCOPE_AGENT);
        if (__all((int)(v >= target))) break;
      }
      __builtin_amdgcn_sched_barrier(0);  // nothing crosses the spin

      // h(t) B-frags via relaxed agent atomic loads (MALL-coherent)
      const unsigned long long* hp =
          (const unsigned long long*)(hbuf + (size_t)(t & 1) * (BATCH * HID)
                                      + (size_t)b_my * HID) + q * 2;
      unsigned long long lo[16], hi[16];
      #pragma unroll
      for (int kc = 0; kc < 16; ++kc) {
        lo[kc] = __hip_atomic_load(hp + kc * 8,     __ATOMIC_RELAXED, __HIP_MEMORY_SCOPE_AGENT);
        hi[kc] = __hip_atomic_load(hp + kc * 8 + 1, __ATOMIC_RELAXED, __HIP_MEMORY_SCOPE_AGENT);
      }
      #pragma unroll
      for (int kc = 0; kc < 16; ++kc) {
        h8u u; u.u2[0] = lo[kc]; u.u2[1] = hi[kc];
        #pragma unroll
        for (int mt = 0; mt < 4; ++mt)
          acc[mt] = __builtin_amdgcn_mfma_f32_16x16x32_f16(whh[kc][mt], u.h, acc[mt], 0, 0, 0);
      }
    }

    // gates -> c,h ; each lane owns units J+q*4..+3 for batch col
    h4u hv;
    #pragma unroll
    for (int r = 0; r < 4; ++r) {
      const float ig = fsig(acc[0][r] + bias[0][r]);
      const float fg = fsig(acc[1][r] + bias[1][r]);
      const float gg = ftanh(acc[2][r] + bias[2][r]);
      const float og = fsig(acc[3][r] + bias[3][r]);
      const float cc = fg * c_st[r] + ig * gg;
      c_st[r] = cc;
      const float h = og * ftanh(cc);
      hsum[r] += h;
      hv.h[r] = (_Float16)h;
    }
    // publish h(t+1): relaxed agent atomic store
    unsigned long long* hw =
        (unsigned long long*)(hbuf + (size_t)((t + 1) & 1) * (BATCH * HID)
                              + (size_t)b_my * HID + J + q * 4);
    __hip_atomic_store(hw, hv.u, __ATOMIC_RELAXED, __HIP_MEMORY_SCOPE_AGENT);

    // manual release: wave-wide store-ack drain, then relaxed per-wave flag
    if (t + 1 < T_STEPS) {
      asm volatile("s_waitcnt vmcnt(0)" ::: "memory");
      if (lane == 0)
        __hip_atomic_store(myflg + wid, (unsigned)(t + 1), __ATOMIC_RELAXED,
                           __HIP_MEMORY_SCOPE_AGENT);

      // xp(t+1) NOW — inside the flag-propagation window (off serial path)
      #pragma unroll
      for (int mt = 0; mt < 4; ++mt) acc[mt] = (f32x4){0.f, 0.f, 0.f, 0.f};
      #pragma unroll
      for (int xc = 0; xc < 4; ++xc) {
        half8 xb = cvt8(xraw[2 * xc], xraw[2 * xc + 1]);
        #pragma unroll
        for (int mt = 0; mt < 4; ++mt)
          acc[mt] = __builtin_amdgcn_mfma_f32_16x16x32_f16(wih[xc][mt], xb, acc[mt], 0, 0, 0);
      }
    }
  }

  // epilogue: logits += mean_h * W_lin^T (bias pre-set by init kernel)
  const float inv = 1.0f / (float)T_STEPS;
  float m[4];
  #pragma unroll
  for (int r = 0; r < 4; ++r) m[r] = hsum[r] * inv;
  #pragma unroll
  for (int cls = 0; cls < 10; ++cls) {
    f32x4 wl = *(const f32x4*)(Wlin + (size_t)cls * HID + J + q * 4);
    float p = m[0] * wl[0] + m[1] * wl[1] + m[2] * wl[2] + m[3] * wl[3];
    p += __shfl_xor(p, 16, 64);
    p += __shfl_xor(p, 32, 64);
    if (q == 0) atomicAdd(out + b_my * 10 + cls, p);
  }
}

__global__ void init_out(const float* __restrict__ blin, float* __restrict__ out) {
  const int i = blockIdx.x * blockDim.x + threadIdx.x;
  if (i < BATCH * 10) out[i] = blin[i % 10];
}

extern "C" void kernel_launch(void* const* d_in, const int* in_sizes, int n_in,
                              void* d_out, int out_size, void* d_ws, size_t ws_size,
                              hipStream_t stream) {
  const float* X    = (const float*)d_in[0];
  const float* Wih  = (const float*)d_in[1];
  const float* Whh  = (const float*)d_in[2];
  const float* bih  = (const float*)d_in[3];
  const float* bhh  = (const float*)d_in[4];
  const float* Wlin = (const float*)d_in[5];
  const float* blin = (const float*)d_in[6];
  float* out = (float*)d_out;

  if (ws_size < (size_t)WS_NEEDED) return;

  _Float16* hbuf = (_Float16*)d_ws;
  unsigned* flg  = (unsigned*)((char*)d_ws + FLG_OFF);

  hipMemsetAsync(d_ws, 0, WS_NEEDED, stream);
  init_out<<<10, 256, 0, stream>>>(blin, out);
  lstm_persistent<<<128, 256, 0, stream>>>(X, Wih, Whh, bih, bhh, Wlin, out,
                                           hbuf, flg);
}